// Round 8
// baseline (234.955 us; speedup 1.0000x reference)
//
#include <hip/hip_runtime.h>
#include <hip/hip_bf16.h>
#include <math.h>

#define N_NODES 20000
#define N_EDGES 320000
#define ET (N_EDGES + N_NODES)   // with self loops = 340000
#define IN_C 512
#define HEADS 8
#define HID 32
#define HH (HEADS * HID)         // 256
#define OUT_C 40
#define NEG_SLOPE 0.2f

typedef __attribute__((ext_vector_type(8))) short short8;
typedef __attribute__((ext_vector_type(4))) float floatx4;

static __device__ __forceinline__ unsigned short f2bf(float f) {
  __hip_bfloat16 h = __float2bfloat16(f);
  return *(unsigned short*)&h;
}
static __device__ __forceinline__ float bf2f_lo(unsigned int u) {
  return __uint_as_float(u << 16);
}
static __device__ __forceinline__ float bf2f_hi(unsigned int u) {
  return __uint_as_float(u & 0xFFFF0000u);
}

// ================= L1: w1/w2 -> bf16 (w2 transposed)  +  edge count ==========
#define WCONV_BLOCKS (IN_C * HH / 256)          // 512
#define W2CONV_BLOCKS (HH * OUT_C / 256)        // 40
#define COUNT_BLOCKS ((ET + 255) / 256)         // 1329
__global__ __launch_bounds__(256) void prep_kernel(
    const float* __restrict__ w1, const float* __restrict__ w2,
    const int* __restrict__ ei, unsigned short* __restrict__ wbT,
    unsigned short* __restrict__ w2bT, int* __restrict__ deg) {
  if (blockIdx.x < WCONV_BLOCKS) {
    int j = blockIdx.x * 256 + threadIdx.x;     // coalesced read of w1
    int k = j >> 8, n = j & 255;
    wbT[(size_t)n * IN_C + k] = f2bf(w1[j]);
  } else if (blockIdx.x < WCONV_BLOCKS + W2CONV_BLOCKS) {
    int j = (blockIdx.x - WCONV_BLOCKS) * 256 + threadIdx.x;  // 10240
    int k = j / OUT_C, oc = j % OUT_C;
    w2bT[oc * HH + k] = f2bf(w2[j]);
  } else {
    int e = (blockIdx.x - WCONV_BLOCKS - W2CONV_BLOCKS) * 256 + threadIdx.x;
    if (e < ET) {
      int dst = (e < N_EDGES) ? ei[N_EDGES + e] : (e - N_EDGES);
      atomicAdd(&deg[dst], 1);
    }
  }
}

// ================= L2: GEMM1 (MFMA bf16, f32 A staged+converted) + CSR scan ==
#define BM 64
#define BN 128
#define BK 32
#define APAD 40   // row stride in shorts (80B)
#define GY ((N_NODES + BM - 1) / BM)            // 313
#define GEMM_BLOCKS (2 * GY)                    // 626
__global__ __launch_bounds__(256) void gemm1_kernel(
    const float* __restrict__ X, const unsigned short* __restrict__ BT,
    const float* __restrict__ bias, unsigned short* __restrict__ C,
    const int* __restrict__ deg, int* __restrict__ offs, int* __restrict__ cursor) {
  if (blockIdx.x >= GEMM_BLOCKS) {
    // ---- CSR exclusive scan: 250 threads x 80 nodes, register-buffered ----
    __shared__ int wsum[4];
    int t = threadIdx.x;
    int4 buf[20];
    int s = 0;
    if (t < 250) {
      const int4* dp = (const int4*)deg + t * 20;
#pragma unroll
      for (int i = 0; i < 20; i++) {
        buf[i] = dp[i];                      // independent loads — pipelined
        s += buf[i].x + buf[i].y + buf[i].z + buf[i].w;
      }
    }
    int lane = t & 63, w = t >> 6;
    int inc = s;
    for (int o = 1; o < 64; o <<= 1) {
      int u = __shfl_up(inc, o, 64);
      if (lane >= o) inc += u;
    }
    if (lane == 63) wsum[w] = inc;
    __syncthreads();
    int waveOff = 0;
    for (int i = 0; i < w; i++) waveOff += wsum[i];
    int running = waveOff + inc - s;         // exclusive thread offset
    if (t < 250) {
      int base = t * 80;
#pragma unroll
      for (int i = 0; i < 20; i++) {
        int4 v = buf[i];
        int4 o;
        o.x = running;
        o.y = o.x + v.x;
        o.z = o.y + v.y;
        o.w = o.z + v.z;
        running = o.w + v.w;
        *(int4*)(offs + base + i * 4) = o;
        *(int4*)(cursor + base + i * 4) = o;
      }
    }
    if (t == 0) offs[N_NODES] = ET;
    return;
  }
  // ---- GEMM tile ----
  __shared__ unsigned short As[BM][APAD];   // [64][40]
  __shared__ unsigned short Bs[BN][APAD];   // [128][40]
  const int tid = threadIdx.x;
  const int lane = tid & 63, wave = tid >> 6;
  const int wm = (wave & 1) * 32;
  const int wn = (wave >> 1) * 64;
  const int r16 = lane & 15, q = lane >> 4;
  const int bx = blockIdx.x & 1, by = blockIdx.x >> 1;
  const int rowBase = by * BM;
  const int colBase = bx * BN;
  floatx4 acc[2][4] = {};

  for (int k0 = 0; k0 < IN_C; k0 += BK) {
    {
      int row = tid >> 2, kc = (tid & 3) * 8;
      int arow = rowBase + row;
      float4 v0 = make_float4(0.f, 0.f, 0.f, 0.f), v1 = v0;
      if (arow < N_NODES) {
        const float* p = X + (size_t)arow * IN_C + k0 + kc;
        v0 = *(const float4*)p;
        v1 = *(const float4*)(p + 4);
      }
      unsigned short tmp[8] = {f2bf(v0.x), f2bf(v0.y), f2bf(v0.z), f2bf(v0.w),
                               f2bf(v1.x), f2bf(v1.y), f2bf(v1.z), f2bf(v1.w)};
      *(float4*)&As[row][kc] = *(const float4*)tmp;
    }
#pragma unroll
    for (int i = 0; i < 2; i++) {
      int c = tid + i * 256;
      int row = c >> 2, kc = (c & 3) * 8;
      float4 v = *(const float4*)(BT + (size_t)(colBase + row) * IN_C + k0 + kc);
      *(float4*)&Bs[row][kc] = v;
    }
    __syncthreads();
    short8 afrag[2], bfrag[4];
#pragma unroll
    for (int mt = 0; mt < 2; mt++)
      afrag[mt] = *(const short8*)&As[wm + mt * 16 + r16][q * 8];
#pragma unroll
    for (int nt = 0; nt < 4; nt++)
      bfrag[nt] = *(const short8*)&Bs[wn + nt * 16 + r16][q * 8];
#pragma unroll
    for (int mt = 0; mt < 2; mt++)
#pragma unroll
      for (int nt = 0; nt < 4; nt++)
        acc[mt][nt] = __builtin_amdgcn_mfma_f32_16x16x32_bf16(
            afrag[mt], bfrag[nt], acc[mt][nt], 0, 0, 0);
    __syncthreads();
  }
#pragma unroll
  for (int mt = 0; mt < 2; mt++) {
#pragma unroll
    for (int nt = 0; nt < 4; nt++) {
      int col = colBase + wn + nt * 16 + r16;
      float bb = bias[col];
#pragma unroll
      for (int r = 0; r < 4; r++) {
        int row = rowBase + wm + mt * 16 + q * 4 + r;
        if (row < N_NODES) C[(size_t)row * HH + col] = f2bf(acc[mt][nt][r] + bb);
      }
    }
  }
}

// ================= L3: CSR fill + attn1 (wave-per-node dots) =================
#define FILL_BLOCKS ((ET + 255) / 256)          // 1329
#define ATTN1_BLOCKS (N_NODES / 4)              // 5000
__global__ __launch_bounds__(256) void fill_attn1_kernel(
    const int* __restrict__ ei, int* __restrict__ cursor, int* __restrict__ csr,
    const unsigned short* __restrict__ h1b, const float* __restrict__ asrc,
    const float* __restrict__ adst, float* __restrict__ as1, float* __restrict__ ad1) {
  if (blockIdx.x < FILL_BLOCKS) {
    int e = blockIdx.x * 256 + threadIdx.x;
    if (e >= ET) return;
    int src, dst;
    if (e < N_EDGES) { src = ei[e]; dst = ei[N_EDGES + e]; }
    else { src = e - N_EDGES; dst = src; }
    int pos = atomicAdd(&cursor[dst], 1);
    csr[pos] = src;
  } else {
    int wave = threadIdx.x >> 6, lane = threadIdx.x & 63;
    int n = (blockIdx.x - FILL_BLOCKS) * 4 + wave;   // exact: 5000*4 = 20000
    int c4 = lane * 4;
    uint2 raw = *(const uint2*)(h1b + (size_t)n * HH + c4);
    float h0 = bf2f_lo(raw.x), h1 = bf2f_hi(raw.x);
    float h2 = bf2f_lo(raw.y), h3 = bf2f_hi(raw.y);
    float4 sa = *(const float4*)(asrc + c4);
    float4 sd = *(const float4*)(adst + c4);
    float ps = h0 * sa.x + h1 * sa.y + h2 * sa.z + h3 * sa.w;
    float pd = h0 * sd.x + h1 * sd.y + h2 * sd.z + h3 * sd.w;
#pragma unroll
    for (int o = 4; o > 0; o >>= 1) {
      ps += __shfl_down(ps, o, 8);
      pd += __shfl_down(pd, o, 8);
    }
    if ((lane & 7) == 0) {
      as1[n * HEADS + (lane >> 3)] = ps;
      ad1[n * HEADS + (lane >> 3)] = pd;
    }
  }
}

// ================= L4: fused agg1 + GEMM2(MFMA) + attn2 ======================
// Block = 16 nodes, 4 waves. Phase A: each wave gathers 4 nodes (max-free
// softmax, bf16 h1), writes h2 rows as bf16 into LDS (A-fragment layout,
// row stride 264 shorts = 4-bank skew). Phase B: waves 0-2 each compute one
// 16-col tile of h2[16x256] @ w2[256x48] via 8 MFMA; B-fragments preloaded
// from w2bT into registers before Phase A. attn2 dots via width-16 shuffle.
#define NPB 16
#define H2ROW 264
__global__ __launch_bounds__(256) void layer1_fused_kernel(
    const unsigned short* __restrict__ h1b, const float* __restrict__ as1,
    const float* __restrict__ ad1, const int* __restrict__ offs,
    const int* __restrict__ csr, const float* __restrict__ b1,
    const unsigned short* __restrict__ w2bT, const float* __restrict__ b2,
    const float* __restrict__ asrc2, const float* __restrict__ adst2,
    float* __restrict__ h3, float* __restrict__ as2, float* __restrict__ ad2) {
  __shared__ __align__(16) unsigned short h2s[NPB][H2ROW];  // 8448 B
  __shared__ float psum[3][NPB], pdsum[3][NPB];
  const int tid = threadIdx.x;
  const int wave = tid >> 6, lane = tid & 63;
  const int r16 = lane & 15, q = lane >> 4;
  const int nodeBase = blockIdx.x * NPB;

  // preload w2 B-fragments (col tile = wave*16 .. +15); latency hides under A
  short8 bfrag[8];
  float sa = 0.f, sd = 0.f, b2c = 0.f;
  if (wave < 3) {
    int col = wave * 16 + r16;
    int colc = (col < OUT_C) ? col : 0;
#pragma unroll
    for (int s = 0; s < 8; s++)
      bfrag[s] = *(const short8*)(w2bT + colc * HH + s * 32 + q * 8);
    if (col < OUT_C) { sa = asrc2[col]; sd = adst2[col]; b2c = b2[col]; }
  }

  // ---- Phase A: gather (4 nodes per wave, 2 edges in flight per iter) ----
  const int half = lane >> 5, sl = lane & 31;
  const int c8 = sl * 8, head = sl >> 2;
  float4 b0 = *(const float4*)(b1 + c8);
  float4 b4 = *(const float4*)(b1 + c8 + 4);
  for (int i = 0; i < 4; i++) {
    int local = wave * 4 + i;
    int n = nodeBase + local;
    int beg = offs[n], end = offs[n + 1];
    float ad = ad1[n * HEADS + head];
    float acc[8] = {};
    float l = 0.f;
#pragma unroll 2
    for (int k = beg + half; k < end; k += 2) {
      int src = csr[k];
      float e = as1[src * HEADS + head] + ad;
      e = (e > 0.f) ? e : NEG_SLOPE * e;
      float p = __expf(e);
      l += p;
      uint4 raw = *(const uint4*)(h1b + ((unsigned)src << 8) + c8);
      acc[0] = fmaf(p, bf2f_lo(raw.x), acc[0]);
      acc[1] = fmaf(p, bf2f_hi(raw.x), acc[1]);
      acc[2] = fmaf(p, bf2f_lo(raw.y), acc[2]);
      acc[3] = fmaf(p, bf2f_hi(raw.y), acc[3]);
      acc[4] = fmaf(p, bf2f_lo(raw.z), acc[4]);
      acc[5] = fmaf(p, bf2f_hi(raw.z), acc[5]);
      acc[6] = fmaf(p, bf2f_lo(raw.w), acc[6]);
      acc[7] = fmaf(p, bf2f_hi(raw.w), acc[7]);
    }
#pragma unroll
    for (int j = 0; j < 8; j++) acc[j] += __shfl_xor(acc[j], 32, 64);
    l += __shfl_xor(l, 32, 64);
    if (half == 0) {
      float li = 1.f / (l + 1e-16f);
      float v[8];
      v[0] = acc[0] * li + b0.x; v[1] = acc[1] * li + b0.y;
      v[2] = acc[2] * li + b0.z; v[3] = acc[3] * li + b0.w;
      v[4] = acc[4] * li + b4.x; v[5] = acc[5] * li + b4.y;
      v[6] = acc[6] * li + b4.z; v[7] = acc[7] * li + b4.w;
      unsigned short o8[8];
#pragma unroll
      for (int j = 0; j < 8; j++) {
        float e = (v[j] > 0.f) ? v[j] : expm1f(v[j]);   // ELU
        o8[j] = f2bf(e);
      }
      *(uint4*)&h2s[local][c8] = *(const uint4*)o8;
    }
  }
  __syncthreads();

  // ---- Phase B: MFMA [16 x 256] @ [256 x 48] ----
  if (wave < 3) {
    floatx4 dacc = {};
#pragma unroll
    for (int s = 0; s < 8; s++) {
      short8 afrag = *(const short8*)&h2s[r16][s * 32 + q * 8];
      dacc = __builtin_amdgcn_mfma_f32_16x16x32_bf16(afrag, bfrag[s], dacc, 0, 0, 0);
    }
    int col = wave * 16 + r16;
    float psr[4], pdr[4];
#pragma unroll
    for (int r = 0; r < 4; r++) {
      float val = dacc[r] + b2c;
      if (col < OUT_C)
        h3[(size_t)(nodeBase + q * 4 + r) * OUT_C + col] = val;
      psr[r] = val * sa;        // sa/sd are 0 for col >= OUT_C
      pdr[r] = val * sd;
    }
#pragma unroll
    for (int o = 8; o > 0; o >>= 1) {
#pragma unroll
      for (int r = 0; r < 4; r++) {
        psr[r] += __shfl_down(psr[r], o, 16);
        pdr[r] += __shfl_down(pdr[r], o, 16);
      }
    }
    if (r16 == 0) {
#pragma unroll
      for (int r = 0; r < 4; r++) {
        psum[wave][q * 4 + r] = psr[r];
        pdsum[wave][q * 4 + r] = pdr[r];
      }
    }
  }
  __syncthreads();
  if (tid < NPB) {
    as2[nodeBase + tid] = psum[0][tid] + psum[1][tid] + psum[2][tid];
    ad2[nodeBase + tid] = pdsum[0][tid] + pdsum[1][tid] + pdsum[2][tid];
  }
}

// ================= L5: agg2 (max-free softmax + gather) + log_softmax ========
__global__ __launch_bounds__(256) void agg2_kernel(
    const float* __restrict__ h3, const float* __restrict__ as2,
    const float* __restrict__ ad2, const int* __restrict__ offs,
    const int* __restrict__ csr, const float* __restrict__ b2,
    float* __restrict__ out) {
  int n = blockIdx.x * 4 + (threadIdx.x >> 6);
  int t = threadIdx.x & 63;
  bool act = (t < OUT_C);
  int beg = offs[n], end = offs[n + 1];
  float ad = ad2[n];
  float l = 0.f, acc = 0.f;
#pragma unroll 2
  for (int k = beg; k < end; k++) {
    int src = csr[k];
    float e = as2[src] + ad;
    e = (e > 0.f) ? e : NEG_SLOPE * e;
    float p = __expf(e);
    l += p;
    float hv = act ? h3[(size_t)src * OUT_C + t] : 0.f;
    acc = fmaf(p, hv, acc);
  }
  float v = acc / (l + 1e-16f) + (act ? b2[t] : 0.f);
  float x = act ? v : -INFINITY;
  float mx = x;
  for (int o = 32; o > 0; o >>= 1) mx = fmaxf(mx, __shfl_down(mx, o, 64));
  mx = __shfl(mx, 0, 64);
  float ex = act ? __expf(v - mx) : 0.f;
  float s = ex;
  for (int o = 32; o > 0; o >>= 1) s += __shfl_down(s, o, 64);
  s = __shfl(s, 0, 64);
  if (act) out[(size_t)n * OUT_C + t] = v - mx - logf(s);
}

extern "C" void kernel_launch(void* const* d_in, const int* in_sizes, int n_in,
                              void* d_out, int out_size, void* d_ws, size_t ws_size,
                              hipStream_t stream) {
  const float* x     = (const float*)d_in[0];
  const int*   ei    = (const int*)d_in[1];
  const float* w1    = (const float*)d_in[2];
  const float* asrc1 = (const float*)d_in[3];
  const float* adst1 = (const float*)d_in[4];
  const float* b1    = (const float*)d_in[5];
  const float* w2    = (const float*)d_in[6];
  const float* asrc2 = (const float*)d_in[7];
  const float* adst2 = (const float*)d_in[8];
  const float* b2    = (const float*)d_in[9];
  float* out = (float*)d_out;

  // workspace carve-up. All extents keep 16B alignment for int4/float4 ops.
  float* fw = (float*)d_ws;
  float* as1   = fw;  fw += (size_t)N_NODES * HEADS;
  float* ad1   = fw;  fw += (size_t)N_NODES * HEADS;
  float* h3    = fw;  fw += (size_t)N_NODES * OUT_C;
  float* as2   = fw;  fw += N_NODES;
  float* ad2   = fw;  fw += N_NODES;
  unsigned short* h1b  = (unsigned short*)fw;  fw += (size_t)N_NODES * HH / 2;
  unsigned short* wbT  = (unsigned short*)fw;  fw += (size_t)IN_C * HH / 2;
  unsigned short* w2bT = (unsigned short*)fw;  fw += (size_t)HH * OUT_C / 2;
  int* deg    = (int*)fw;
  int* offs   = deg + N_NODES;            // N+1 (+3 pad)
  int* cursor = offs + N_NODES + 4;       // 16B-aligned
  int* csr    = cursor + N_NODES;         // ET

  hipMemsetAsync(deg, 0, N_NODES * sizeof(int), stream);

  prep_kernel<<<WCONV_BLOCKS + W2CONV_BLOCKS + COUNT_BLOCKS, 256, 0, stream>>>(
      w1, w2, ei, wbT, w2bT, deg);
  gemm1_kernel<<<GEMM_BLOCKS + 1, 256, 0, stream>>>(x, wbT, b1, h1b, deg, offs, cursor);
  fill_attn1_kernel<<<FILL_BLOCKS + ATTN1_BLOCKS, 256, 0, stream>>>(
      ei, cursor, csr, h1b, asrc1, adst1, as1, ad1);
  layer1_fused_kernel<<<N_NODES / NPB, 256, 0, stream>>>(
      h1b, as1, ad1, offs, csr, b1, w2bT, b2, asrc2, adst2, h3, as2, ad2);
  agg2_kernel<<<N_NODES / 4, 256, 0, stream>>>(h3, as2, ad2, offs, csr, b2, out);
}

// Round 9
// 232.386 us; speedup vs baseline: 1.0111x; 1.0111x over previous
//
#include <hip/hip_runtime.h>
#include <hip/hip_bf16.h>
#include <math.h>

#define N_NODES 20000
#define N_EDGES 320000
#define ET (N_EDGES + N_NODES)   // with self loops = 340000
#define IN_C 512
#define HEADS 8
#define HID 32
#define HH (HEADS * HID)         // 256
#define OUT_C 40
#define NEG_SLOPE 0.2f

typedef __attribute__((ext_vector_type(8))) short short8;
typedef __attribute__((ext_vector_type(4))) float floatx4;

static __device__ __forceinline__ unsigned short f2bf(float f) {
  __hip_bfloat16 h = __float2bfloat16(f);
  return *(unsigned short*)&h;
}
static __device__ __forceinline__ float bf2f_lo(unsigned int u) {
  return __uint_as_float(u << 16);
}
static __device__ __forceinline__ float bf2f_hi(unsigned int u) {
  return __uint_as_float(u & 0xFFFF0000u);
}

// ================= L1: w1/w2 -> bf16 (w2 transposed)  +  edge count ==========
#define WCONV_BLOCKS (IN_C * HH / 256)          // 512
#define W2CONV_BLOCKS (HH * OUT_C / 256)        // 40
#define COUNT_BLOCKS ((ET + 255) / 256)         // 1329
__global__ __launch_bounds__(256) void prep_kernel(
    const float* __restrict__ w1, const float* __restrict__ w2,
    const int* __restrict__ ei, unsigned short* __restrict__ wbT,
    unsigned short* __restrict__ w2bT, int* __restrict__ deg) {
  if (blockIdx.x < WCONV_BLOCKS) {
    int j = blockIdx.x * 256 + threadIdx.x;     // coalesced read of w1
    int k = j >> 8, n = j & 255;
    wbT[(size_t)n * IN_C + k] = f2bf(w1[j]);
  } else if (blockIdx.x < WCONV_BLOCKS + W2CONV_BLOCKS) {
    int j = (blockIdx.x - WCONV_BLOCKS) * 256 + threadIdx.x;  // 10240
    int k = j / OUT_C, oc = j % OUT_C;
    w2bT[oc * HH + k] = f2bf(w2[j]);
  } else {
    int e = (blockIdx.x - WCONV_BLOCKS - W2CONV_BLOCKS) * 256 + threadIdx.x;
    if (e < ET) {
      int dst = (e < N_EDGES) ? ei[N_EDGES + e] : (e - N_EDGES);
      atomicAdd(&deg[dst], 1);
    }
  }
}

// ================= L2: GEMM1 (MFMA bf16, f32 A staged+converted) + CSR scan ==
#define BM 64
#define BN 128
#define BK 32
#define APAD 40   // row stride in shorts (80B)
#define GY ((N_NODES + BM - 1) / BM)            // 313
#define GEMM_BLOCKS (2 * GY)                    // 626
__global__ __launch_bounds__(256) void gemm1_kernel(
    const float* __restrict__ X, const unsigned short* __restrict__ BT,
    const float* __restrict__ bias, unsigned short* __restrict__ C,
    const int* __restrict__ deg, int* __restrict__ offs, int* __restrict__ cursor) {
  if (blockIdx.x >= GEMM_BLOCKS) {
    // ---- CSR exclusive scan: 250 threads x 80 nodes, register-buffered ----
    __shared__ int wsum[4];
    int t = threadIdx.x;
    int4 buf[20];
    int s = 0;
    if (t < 250) {
      const int4* dp = (const int4*)deg + t * 20;
#pragma unroll
      for (int i = 0; i < 20; i++) {
        buf[i] = dp[i];                      // independent loads — pipelined
        s += buf[i].x + buf[i].y + buf[i].z + buf[i].w;
      }
    }
    int lane = t & 63, w = t >> 6;
    int inc = s;
    for (int o = 1; o < 64; o <<= 1) {
      int u = __shfl_up(inc, o, 64);
      if (lane >= o) inc += u;
    }
    if (lane == 63) wsum[w] = inc;
    __syncthreads();
    int waveOff = 0;
    for (int i = 0; i < w; i++) waveOff += wsum[i];
    int running = waveOff + inc - s;         // exclusive thread offset
    if (t < 250) {
      int base = t * 80;
#pragma unroll
      for (int i = 0; i < 20; i++) {
        int4 v = buf[i];
        int4 o;
        o.x = running;
        o.y = o.x + v.x;
        o.z = o.y + v.y;
        o.w = o.z + v.z;
        running = o.w + v.w;
        *(int4*)(offs + base + i * 4) = o;
        *(int4*)(cursor + base + i * 4) = o;
      }
    }
    if (t == 0) offs[N_NODES] = ET;
    return;
  }
  // ---- GEMM tile ----
  __shared__ unsigned short As[BM][APAD];   // [64][40]
  __shared__ unsigned short Bs[BN][APAD];   // [128][40]
  const int tid = threadIdx.x;
  const int lane = tid & 63, wave = tid >> 6;
  const int wm = (wave & 1) * 32;
  const int wn = (wave >> 1) * 64;
  const int r16 = lane & 15, q = lane >> 4;
  const int bx = blockIdx.x & 1, by = blockIdx.x >> 1;
  const int rowBase = by * BM;
  const int colBase = bx * BN;
  floatx4 acc[2][4] = {};

  for (int k0 = 0; k0 < IN_C; k0 += BK) {
    {
      int row = tid >> 2, kc = (tid & 3) * 8;
      int arow = rowBase + row;
      float4 v0 = make_float4(0.f, 0.f, 0.f, 0.f), v1 = v0;
      if (arow < N_NODES) {
        const float* p = X + (size_t)arow * IN_C + k0 + kc;
        v0 = *(const float4*)p;
        v1 = *(const float4*)(p + 4);
      }
      unsigned short tmp[8] = {f2bf(v0.x), f2bf(v0.y), f2bf(v0.z), f2bf(v0.w),
                               f2bf(v1.x), f2bf(v1.y), f2bf(v1.z), f2bf(v1.w)};
      *(float4*)&As[row][kc] = *(const float4*)tmp;
    }
#pragma unroll
    for (int i = 0; i < 2; i++) {
      int c = tid + i * 256;
      int row = c >> 2, kc = (c & 3) * 8;
      float4 v = *(const float4*)(BT + (size_t)(colBase + row) * IN_C + k0 + kc);
      *(float4*)&Bs[row][kc] = v;
    }
    __syncthreads();
    short8 afrag[2], bfrag[4];
#pragma unroll
    for (int mt = 0; mt < 2; mt++)
      afrag[mt] = *(const short8*)&As[wm + mt * 16 + r16][q * 8];
#pragma unroll
    for (int nt = 0; nt < 4; nt++)
      bfrag[nt] = *(const short8*)&Bs[wn + nt * 16 + r16][q * 8];
#pragma unroll
    for (int mt = 0; mt < 2; mt++)
#pragma unroll
      for (int nt = 0; nt < 4; nt++)
        acc[mt][nt] = __builtin_amdgcn_mfma_f32_16x16x32_bf16(
            afrag[mt], bfrag[nt], acc[mt][nt], 0, 0, 0);
    __syncthreads();
  }
#pragma unroll
  for (int mt = 0; mt < 2; mt++) {
#pragma unroll
    for (int nt = 0; nt < 4; nt++) {
      int col = colBase + wn + nt * 16 + r16;
      float bb = bias[col];
#pragma unroll
      for (int r = 0; r < 4; r++) {
        int row = rowBase + wm + mt * 16 + q * 4 + r;
        if (row < N_NODES) C[(size_t)row * HH + col] = f2bf(acc[mt][nt][r] + bb);
      }
    }
  }
}

// ================= L3: CSR fill + attn1 (wave-per-node dots) =================
#define FILL_BLOCKS ((ET + 255) / 256)          // 1329
#define ATTN1_BLOCKS (N_NODES / 4)              // 5000
__global__ __launch_bounds__(256) void fill_attn1_kernel(
    const int* __restrict__ ei, int* __restrict__ cursor, int* __restrict__ csr,
    const unsigned short* __restrict__ h1b, const float* __restrict__ asrc,
    const float* __restrict__ adst, float* __restrict__ as1, float* __restrict__ ad1) {
  if (blockIdx.x < FILL_BLOCKS) {
    int e = blockIdx.x * 256 + threadIdx.x;
    if (e >= ET) return;
    int src, dst;
    if (e < N_EDGES) { src = ei[e]; dst = ei[N_EDGES + e]; }
    else { src = e - N_EDGES; dst = src; }
    int pos = atomicAdd(&cursor[dst], 1);
    csr[pos] = src;
  } else {
    int wave = threadIdx.x >> 6, lane = threadIdx.x & 63;
    int n = (blockIdx.x - FILL_BLOCKS) * 4 + wave;   // exact: 5000*4 = 20000
    int c4 = lane * 4;
    uint2 raw = *(const uint2*)(h1b + (size_t)n * HH + c4);
    float h0 = bf2f_lo(raw.x), h1 = bf2f_hi(raw.x);
    float h2 = bf2f_lo(raw.y), h3 = bf2f_hi(raw.y);
    float4 sa = *(const float4*)(asrc + c4);
    float4 sd = *(const float4*)(adst + c4);
    float ps = h0 * sa.x + h1 * sa.y + h2 * sa.z + h3 * sa.w;
    float pd = h0 * sd.x + h1 * sd.y + h2 * sd.z + h3 * sd.w;
#pragma unroll
    for (int o = 4; o > 0; o >>= 1) {
      ps += __shfl_down(ps, o, 8);
      pd += __shfl_down(pd, o, 8);
    }
    if ((lane & 7) == 0) {
      as1[n * HEADS + (lane >> 3)] = ps;
      ad1[n * HEADS + (lane >> 3)] = pd;
    }
  }
}

// ================= L4: fused agg1 + GEMM2(MFMA) + attn2 ======================
// Block = 16 nodes, 4 waves. Phase A quarter-split: 4 edge streams per wave,
// 16 lanes/edge, 32 B/lane (2x uint4) -> ~16 outstanding loads per wave.
// Streams combined via shfl_xor(16/32). Phase B: waves 0-2 each compute one
// 16-col tile of h2[16x256] @ w2[256x48] via 8 MFMA (B-fragments preloaded).
#define NPB 16
#define H2ROW 264
__global__ __launch_bounds__(256) void layer1_fused_kernel(
    const unsigned short* __restrict__ h1b, const float* __restrict__ as1,
    const float* __restrict__ ad1, const int* __restrict__ offs,
    const int* __restrict__ csr, const float* __restrict__ b1,
    const unsigned short* __restrict__ w2bT, const float* __restrict__ b2,
    const float* __restrict__ asrc2, const float* __restrict__ adst2,
    float* __restrict__ h3, float* __restrict__ as2, float* __restrict__ ad2) {
  __shared__ __align__(16) unsigned short h2s[NPB][H2ROW];  // 8448 B
  __shared__ float psum[3][NPB], pdsum[3][NPB];
  const int tid = threadIdx.x;
  const int wave = tid >> 6, lane = tid & 63;
  const int r16 = lane & 15, q = lane >> 4;
  const int nodeBase = blockIdx.x * NPB;

  // preload w2 B-fragments (col tile = wave*16 .. +15); latency hides under A
  short8 bfrag[8];
  float sa = 0.f, sd = 0.f, b2c = 0.f;
  if (wave < 3) {
    int col = wave * 16 + r16;
    int colc = (col < OUT_C) ? col : 0;
#pragma unroll
    for (int s = 0; s < 8; s++)
      bfrag[s] = *(const short8*)(w2bT + colc * HH + s * 32 + q * 8);
    if (col < OUT_C) { sa = asrc2[col]; sd = adst2[col]; b2c = b2[col]; }
  }

  // ---- Phase A: gather, quarter-split (4 streams x 16 lanes) ----
  const int strm = lane >> 4;          // 0..3: edge stream
  const int l16 = lane & 15;
  const int c16 = l16 * 16;            // 16 channels per lane (32 B)
  const int head = l16 >> 1;           // 16-ch group sits inside one 32-ch head
  float4 bb0 = *(const float4*)(b1 + c16);
  float4 bb1 = *(const float4*)(b1 + c16 + 4);
  float4 bb2 = *(const float4*)(b1 + c16 + 8);
  float4 bb3 = *(const float4*)(b1 + c16 + 12);
  for (int i = 0; i < 4; i++) {
    int local = wave * 4 + i;
    int n = nodeBase + local;
    int beg = offs[n], end = offs[n + 1];
    float ad = ad1[n * HEADS + head];
    float acc[16] = {};
    float l = 0.f;
#pragma unroll 2
    for (int k = beg + strm; k < end; k += 4) {
      int src = csr[k];
      float e = as1[src * HEADS + head] + ad;
      e = (e > 0.f) ? e : NEG_SLOPE * e;
      float p = __expf(e);
      l += p;
      const unsigned short* hp = h1b + ((unsigned)src << 8) + c16;
      uint4 r0 = *(const uint4*)hp;
      uint4 r1 = *(const uint4*)(hp + 8);
      acc[0]  = fmaf(p, bf2f_lo(r0.x), acc[0]);
      acc[1]  = fmaf(p, bf2f_hi(r0.x), acc[1]);
      acc[2]  = fmaf(p, bf2f_lo(r0.y), acc[2]);
      acc[3]  = fmaf(p, bf2f_hi(r0.y), acc[3]);
      acc[4]  = fmaf(p, bf2f_lo(r0.z), acc[4]);
      acc[5]  = fmaf(p, bf2f_hi(r0.z), acc[5]);
      acc[6]  = fmaf(p, bf2f_lo(r0.w), acc[6]);
      acc[7]  = fmaf(p, bf2f_hi(r0.w), acc[7]);
      acc[8]  = fmaf(p, bf2f_lo(r1.x), acc[8]);
      acc[9]  = fmaf(p, bf2f_hi(r1.x), acc[9]);
      acc[10] = fmaf(p, bf2f_lo(r1.y), acc[10]);
      acc[11] = fmaf(p, bf2f_hi(r1.y), acc[11]);
      acc[12] = fmaf(p, bf2f_lo(r1.z), acc[12]);
      acc[13] = fmaf(p, bf2f_hi(r1.z), acc[13]);
      acc[14] = fmaf(p, bf2f_lo(r1.w), acc[14]);
      acc[15] = fmaf(p, bf2f_hi(r1.w), acc[15]);
    }
#pragma unroll
    for (int j = 0; j < 16; j++) {
      acc[j] += __shfl_xor(acc[j], 16, 64);
      acc[j] += __shfl_xor(acc[j], 32, 64);
    }
    l += __shfl_xor(l, 16, 64);
    l += __shfl_xor(l, 32, 64);
    if (strm == 0) {
      float li = 1.f / (l + 1e-16f);
      float v[16];
      v[0]  = acc[0]  * li + bb0.x; v[1]  = acc[1]  * li + bb0.y;
      v[2]  = acc[2]  * li + bb0.z; v[3]  = acc[3]  * li + bb0.w;
      v[4]  = acc[4]  * li + bb1.x; v[5]  = acc[5]  * li + bb1.y;
      v[6]  = acc[6]  * li + bb1.z; v[7]  = acc[7]  * li + bb1.w;
      v[8]  = acc[8]  * li + bb2.x; v[9]  = acc[9]  * li + bb2.y;
      v[10] = acc[10] * li + bb2.z; v[11] = acc[11] * li + bb2.w;
      v[12] = acc[12] * li + bb3.x; v[13] = acc[13] * li + bb3.y;
      v[14] = acc[14] * li + bb3.z; v[15] = acc[15] * li + bb3.w;
      unsigned short o16[16];
#pragma unroll
      for (int j = 0; j < 16; j++) {
        float e = (v[j] > 0.f) ? v[j] : expm1f(v[j]);   // ELU
        o16[j] = f2bf(e);
      }
      *(uint4*)&h2s[local][c16] = *(const uint4*)&o16[0];
      *(uint4*)&h2s[local][c16 + 8] = *(const uint4*)&o16[8];
    }
  }
  __syncthreads();

  // ---- Phase B: MFMA [16 x 256] @ [256 x 48] ----
  if (wave < 3) {
    floatx4 dacc = {};
#pragma unroll
    for (int s = 0; s < 8; s++) {
      short8 afrag = *(const short8*)&h2s[r16][s * 32 + q * 8];
      dacc = __builtin_amdgcn_mfma_f32_16x16x32_bf16(afrag, bfrag[s], dacc, 0, 0, 0);
    }
    int col = wave * 16 + r16;
    float psr[4], pdr[4];
#pragma unroll
    for (int r = 0; r < 4; r++) {
      float val = dacc[r] + b2c;
      if (col < OUT_C)
        h3[(size_t)(nodeBase + q * 4 + r) * OUT_C + col] = val;
      psr[r] = val * sa;        // sa/sd are 0 for col >= OUT_C
      pdr[r] = val * sd;
    }
#pragma unroll
    for (int o = 8; o > 0; o >>= 1) {
#pragma unroll
      for (int r = 0; r < 4; r++) {
        psr[r] += __shfl_down(psr[r], o, 16);
        pdr[r] += __shfl_down(pdr[r], o, 16);
      }
    }
    if (r16 == 0) {
#pragma unroll
      for (int r = 0; r < 4; r++) {
        psum[wave][q * 4 + r] = psr[r];
        pdsum[wave][q * 4 + r] = pdr[r];
      }
    }
  }
  __syncthreads();
  if (tid < NPB) {
    as2[nodeBase + tid] = psum[0][tid] + psum[1][tid] + psum[2][tid];
    ad2[nodeBase + tid] = pdsum[0][tid] + pdsum[1][tid] + pdsum[2][tid];
  }
}

// ================= L5: agg2 (max-free softmax, dual-stream) + log_softmax ====
__global__ __launch_bounds__(256) void agg2_kernel(
    const float* __restrict__ h3, const float* __restrict__ as2,
    const float* __restrict__ ad2, const int* __restrict__ offs,
    const int* __restrict__ csr, const float* __restrict__ b2,
    float* __restrict__ out) {
  int n = blockIdx.x * 4 + (threadIdx.x >> 6);
  int t = threadIdx.x & 63;
  bool act = (t < OUT_C);
  int beg = offs[n], end = offs[n + 1];
  float ad = ad2[n];
  // two independent accumulation chains for 2x memory-level parallelism
  float l0 = 0.f, l1 = 0.f, a0 = 0.f, a1 = 0.f;
  int k = beg;
  for (; k + 1 < end; k += 2) {
    int s0 = csr[k], s1 = csr[k + 1];
    float e0 = as2[s0] + ad, e1 = as2[s1] + ad;
    e0 = (e0 > 0.f) ? e0 : NEG_SLOPE * e0;
    e1 = (e1 > 0.f) ? e1 : NEG_SLOPE * e1;
    float p0 = __expf(e0), p1 = __expf(e1);
    l0 += p0; l1 += p1;
    float h0 = act ? h3[(size_t)s0 * OUT_C + t] : 0.f;
    float h1 = act ? h3[(size_t)s1 * OUT_C + t] : 0.f;
    a0 = fmaf(p0, h0, a0);
    a1 = fmaf(p1, h1, a1);
  }
  if (k < end) {
    int s0 = csr[k];
    float e0 = as2[s0] + ad;
    e0 = (e0 > 0.f) ? e0 : NEG_SLOPE * e0;
    float p0 = __expf(e0);
    l0 += p0;
    float h0 = act ? h3[(size_t)s0 * OUT_C + t] : 0.f;
    a0 = fmaf(p0, h0, a0);
  }
  float l = l0 + l1, acc = a0 + a1;
  float v = acc / (l + 1e-16f) + (act ? b2[t] : 0.f);
  float x = act ? v : -INFINITY;
  float mx = x;
  for (int o = 32; o > 0; o >>= 1) mx = fmaxf(mx, __shfl_down(mx, o, 64));
  mx = __shfl(mx, 0, 64);
  float ex = act ? __expf(v - mx) : 0.f;
  float s = ex;
  for (int o = 32; o > 0; o >>= 1) s += __shfl_down(s, o, 64);
  s = __shfl(s, 0, 64);
  if (act) out[(size_t)n * OUT_C + t] = v - mx - logf(s);
}

extern "C" void kernel_launch(void* const* d_in, const int* in_sizes, int n_in,
                              void* d_out, int out_size, void* d_ws, size_t ws_size,
                              hipStream_t stream) {
  const float* x     = (const float*)d_in[0];
  const int*   ei    = (const int*)d_in[1];
  const float* w1    = (const float*)d_in[2];
  const float* asrc1 = (const float*)d_in[3];
  const float* adst1 = (const float*)d_in[4];
  const float* b1    = (const float*)d_in[5];
  const float* w2    = (const float*)d_in[6];
  const float* asrc2 = (const float*)d_in[7];
  const float* adst2 = (const float*)d_in[8];
  const float* b2    = (const float*)d_in[9];
  float* out = (float*)d_out;

  // workspace carve-up. All extents keep 16B alignment for int4/float4 ops.
  float* fw = (float*)d_ws;
  float* as1   = fw;  fw += (size_t)N_NODES * HEADS;
  float* ad1   = fw;  fw += (size_t)N_NODES * HEADS;
  float* h3    = fw;  fw += (size_t)N_NODES * OUT_C;
  float* as2   = fw;  fw += N_NODES;
  float* ad2   = fw;  fw += N_NODES;
  unsigned short* h1b  = (unsigned short*)fw;  fw += (size_t)N_NODES * HH / 2;
  unsigned short* wbT  = (unsigned short*)fw;  fw += (size_t)IN_C * HH / 2;
  unsigned short* w2bT = (unsigned short*)fw;  fw += (size_t)HH * OUT_C / 2;
  int* deg    = (int*)fw;
  int* offs   = deg + N_NODES;            // N+1 (+3 pad)
  int* cursor = offs + N_NODES + 4;       // 16B-aligned
  int* csr    = cursor + N_NODES;         // ET

  hipMemsetAsync(deg, 0, N_NODES * sizeof(int), stream);

  prep_kernel<<<WCONV_BLOCKS + W2CONV_BLOCKS + COUNT_BLOCKS, 256, 0, stream>>>(
      w1, w2, ei, wbT, w2bT, deg);
  gemm1_kernel<<<GEMM_BLOCKS + 1, 256, 0, stream>>>(x, wbT, b1, h1b, deg, offs, cursor);
  fill_attn1_kernel<<<FILL_BLOCKS + ATTN1_BLOCKS, 256, 0, stream>>>(
      ei, cursor, csr, h1b, asrc1, adst1, as1, ad1);
  layer1_fused_kernel<<<N_NODES / NPB, 256, 0, stream>>>(
      h1b, as1, ad1, offs, csr, b1, w2bT, b2, asrc2, adst2, h3, as2, ad2);
  agg2_kernel<<<N_NODES / 4, 256, 0, stream>>>(h3, as2, ad2, offs, csr, b2, out);
}